// Round 13
// baseline (199.414 us; speedup 1.0000x reference)
//
#include <hip/hip_runtime.h>
#include <stdint.h>

#define T_TOK 8192
#define HD 1024
#define NE 16
#define NET 17
#define FD 512
#define CAP 8448            // max tokens/expert 8192 + 255 pad (256-row blocks)
#define MAXWG 448           // 112 row-blocks x 4 col-blocks
#define CPX 56              // MAXWG / 8 XCDs

typedef unsigned int uint;
typedef unsigned short ushort;
typedef __attribute__((ext_vector_type(8))) __bf16 bf16x8;
typedef __attribute__((ext_vector_type(4))) float f32x4;

// ws layout (bytes)
#define OFF_XBF   0ull            // 16 MB   (dead after k_up -> ybuf)
#define OFF_WUPT  16777216ull     // 35.65MB (dead after k_up -> ybuf)
#define OFF_WDT   52428800ull     // 17.83MB
#define OFF_ACT   70254592ull     // 24576 x 1024 B = 25.17MB (compact rows)
#define OFF_EIDX  95420416ull     // inv_a (e0,p0) per token
#define OFF_EW    95485952ull     // inv_b (e1,p1) per token
#define OFF_TOK   95551488ull     // 17*CAP ints
#define OFF_WGT   96125952ull
#define OFF_META  96700416ull
#define OFF_SEL   96704512ull     // int4 per token: (i1, i2, w1 bits, w2 bits)
#define WS_NEEDED (OFF_SEL + 131072ull)
// ybuf: compact 24576 rows x 2048 B = 50,331,648 < OFF_WDT.

// meta: [0..16]=cnt (16=shared=8192), [17]=nRB, [32..144)=rbE, [160..272)=rbLoc,
//       [288..400)=rbRow (compact base), [416..433)=ybase per expert

__device__ __forceinline__ ushort f2bf(float f) {
    uint u = __float_as_uint(f);
    u += 0x7FFFu + ((u >> 16) & 1u);
    return (ushort)(u >> 16);
}
__device__ __forceinline__ float bf2f(ushort u) {
    return __uint_as_float(((uint)u) << 16);
}
__device__ __forceinline__ void gload16(const void* g, void* l) {
    __builtin_amdgcn_global_load_lds(
        (const __attribute__((address_space(1))) void*)g,
        (__attribute__((address_space(3))) void*)l, 16, 0, 0);
}

// ---------------- router: NO global atomics, 4-way K-split, 100% occupancy ----------------
__global__ __launch_bounds__(1024) void k_router(const float* __restrict__ x,
                                                 const float* __restrict__ Wr,
                                                 float* __restrict__ probs,
                                                 ushort* __restrict__ xb,
                                                 int* __restrict__ tok,
                                                 float* __restrict__ wgt,
                                                 int4* __restrict__ sel) {
    __shared__ __align__(16) float wr_s[HD * NE];   // 64 KB fp32
    int tid = threadIdx.x;
    int t0 = blockIdx.x * 16;
#pragma unroll
    for (int i = 0; i < 4; ++i) {
        int idx = (i * 1024 + tid) * 4;
        *(float4*)(&wr_s[idx]) = *(const float4*)(Wr + idx);
    }
#pragma unroll
    for (int p = 0; p < 4; ++p) {
        int r = p * 4 + (tid >> 8);
        int c = (tid & 255) * 4;
        float4 v = *(const float4*)(x + (size_t)(t0 + r) * HD + c);
        ushort4 cc;
        cc.x = f2bf(v.x); cc.y = f2bf(v.y); cc.z = f2bf(v.z); cc.w = f2bf(v.w);
        *(ushort4*)(xb + (size_t)(t0 + r) * HD + c) = cc;
    }
    __syncthreads();
    int t = t0 + (tid >> 6);
    int sub = tid & 63;
    int e = sub & 15, kp = sub >> 4;
    const float* xg = x + (size_t)t * HD + kp * 256;
    const int wb = kp * 256 * NE + e;
    float s0 = 0.f, s1 = 0.f;
#pragma unroll 8
    for (int j = 0; j < 256; j += 4) {
        float4 v = *(const float4*)(xg + j);
        s0 = fmaf(v.x, wr_s[wb + (j + 0) * NE], s0);
        s1 = fmaf(v.y, wr_s[wb + (j + 1) * NE], s1);
        s0 = fmaf(v.z, wr_s[wb + (j + 2) * NE], s0);
        s1 = fmaf(v.w, wr_s[wb + (j + 3) * NE], s1);
    }
    float s = s0 + s1;
    s += __shfl_xor(s, 16);
    s += __shfl_xor(s, 32);
    float m = s;
#pragma unroll
    for (int w = 1; w < 16; w <<= 1) m = fmaxf(m, __shfl_xor(m, w));
    float p = __expf(s - m);
    float sum = p;
#pragma unroll
    for (int w = 1; w < 16; w <<= 1) sum += __shfl_xor(sum, w);
    p /= sum;
    if (kp == 0) probs[(size_t)t * NE + e] = p;
    float m1 = p;
#pragma unroll
    for (int w = 1; w < 16; w <<= 1) m1 = fmaxf(m1, __shfl_xor(m1, w));
    unsigned long long bal = __ballot(p == m1);
    int i1 = __ffs((int)((bal >> (kp * 16)) & 0xFFFFu)) - 1;
    float p2v = (e == i1) ? -1.f : p;
    float m2 = p2v;
#pragma unroll
    for (int w = 1; w < 16; w <<= 1) m2 = fmaxf(m2, __shfl_xor(m2, w));
    bal = __ballot(p2v == m2);
    int i2 = __ffs((int)((bal >> (kp * 16)) & 0xFFFFu)) - 1;
    if (sub == 0) {
        float inv2 = 1.f / (m1 + m2 + 1e-9f);
        sel[t] = make_int4(i1, i2, __float_as_int(m1 * inv2), __float_as_int(m2 * inv2));
        tok[16 * CAP + t] = t;
        wgt[16 * CAP + t] = 1.f;
    }
}

// ---------------- bucket: 16 blocks (one per expert), 16 waves scan 512-token chunks ----------------
__global__ __launch_bounds__(1024) void k_bucket(const int4* __restrict__ sel,
                                                 int* __restrict__ tok,
                                                 float* __restrict__ wgt,
                                                 int2* __restrict__ inva,
                                                 int2* __restrict__ invb,
                                                 int* __restrict__ meta) {
    __shared__ int wcnt[16], wbase[16];
    int e = blockIdx.x;
    int wave = threadIdx.x >> 6;
    int lane = threadIdx.x & 63;
    unsigned long long ltmask = (1ull << lane) - 1ull;
    int tstart = wave * 512;
    int cnt = 0;
#pragma unroll
    for (int it = 0; it < 8; ++it) {
        int4 s = sel[tstart + it * 64 + lane];
        cnt += (int)__popcll(__ballot(s.x == e)) + (int)__popcll(__ballot(s.y == e));
    }
    if (lane == 0) wcnt[wave] = cnt;
    __syncthreads();
    if (threadIdx.x == 0) {
        int acc = 0;
#pragma unroll
        for (int w = 0; w < 16; ++w) { wbase[w] = acc; acc += wcnt[w]; }
        meta[e] = acc;
    }
    __syncthreads();
    int pos = wbase[wave];
#pragma unroll
    for (int it = 0; it < 8; ++it) {
        int t = tstart + it * 64 + lane;
        int4 s = sel[t];
        bool m1 = (s.x == e), m2 = (s.y == e);
        unsigned long long b1 = __ballot(m1), b2 = __ballot(m2);
        int c1 = (int)__popcll(b1);
        if (m1) {
            int q = pos + (int)__popcll(b1 & ltmask);
            tok[e * CAP + q] = t; wgt[e * CAP + q] = __int_as_float(s.z);
            inva[t] = make_int2(e, q);
        }
        if (m2) {
            int q = pos + c1 + (int)__popcll(b2 & ltmask);
            tok[e * CAP + q] = t; wgt[e * CAP + q] = __int_as_float(s.w);
            invb[t] = make_int2(e, q);
        }
        pos += c1 + (int)__popcll(b2);
    }
}

// ---------------- W_up [E][H][2F] fp32 (+shared) -> wupT [17][2F][H] bf16, 64x64 tiles ----------------
__global__ __launch_bounds__(256) void k_tup(const float* __restrict__ Wup,
                                             const float* __restrict__ Wsup,
                                             ushort* __restrict__ dst) {
    __shared__ __align__(16) float tile[64][68];
    int bid = blockIdx.x;
    int e = bid >> 8, rem = bid & 255;
    int h0 = (rem >> 4) * 64, n0 = (rem & 15) * 64;
    const float* src = (e < 16) ? (Wup + (size_t)e * HD * 1024) : Wsup;
    int tid = threadIdx.x;
    int rr = tid >> 4, cc = (tid & 15) * 4;
#pragma unroll
    for (int q = 0; q < 4; ++q) {
        float4 v = *(const float4*)(src + (size_t)(h0 + q * 16 + rr) * 1024 + n0 + cc);
        *(float4*)(&tile[q * 16 + rr][cc]) = v;
    }
    __syncthreads();
#pragma unroll
    for (int q = 0; q < 4; ++q) {
        int nl = q * 16 + rr;
        ushort4 o;
        o.x = f2bf(tile[cc + 0][nl]);
        o.y = f2bf(tile[cc + 1][nl]);
        o.z = f2bf(tile[cc + 2][nl]);
        o.w = f2bf(tile[cc + 3][nl]);
        *(ushort4*)(dst + (size_t)e * 1048576 + (size_t)(n0 + nl) * 1024 + h0 + cc) = o;
    }
}

// ---------------- W_down [E][F][H] fp32 (+shared) -> wdT [17][H][F] bf16, 64x64 tiles ----------------
__global__ __launch_bounds__(256) void k_tdn(const float* __restrict__ Wdn,
                                             const float* __restrict__ Wsdn,
                                             ushort* __restrict__ dst) {
    __shared__ __align__(16) float tile[64][68];
    int bid = blockIdx.x;
    int e = bid >> 7, rem = bid & 127;
    int f0 = (rem >> 4) * 64, h0 = (rem & 15) * 64;
    const float* src = (e < 16) ? (Wdn + (size_t)e * FD * HD) : Wsdn;
    int tid = threadIdx.x;
    int rr = tid >> 4, cc = (tid & 15) * 4;
#pragma unroll
    for (int q = 0; q < 4; ++q) {
        float4 v = *(const float4*)(src + (size_t)(f0 + q * 16 + rr) * 1024 + h0 + cc);
        *(float4*)(&tile[q * 16 + rr][cc]) = v;
    }
    __syncthreads();
#pragma unroll
    for (int q = 0; q < 4; ++q) {
        int hl = q * 16 + rr;
        ushort4 o;
        o.x = f2bf(tile[cc + 0][hl]);
        o.y = f2bf(tile[cc + 1][hl]);
        o.z = f2bf(tile[cc + 2][hl]);
        o.w = f2bf(tile[cc + 3][hl]);
        *(ushort4*)(dst + (size_t)e * 524288 + (size_t)(h0 + hl) * 512 + f0 + cc) = o;
    }
}

// ---------------- finalize: build 256-row blocks, zero pad slots ----------------
__global__ void k_finalize(int* __restrict__ meta, int* __restrict__ tok,
                           float* __restrict__ wgt) {
    __shared__ int sN[NET], sPad[NET];
    int tid = threadIdx.x;
    if (tid == 0) {
        meta[16] = T_TOK;
        int idx = 0, yoff = 0;
        for (int e = 0; e < NET; e++) {
            int n = meta[e];
            int padded = (n + 255) & ~255;
            sN[e] = n; sPad[e] = padded;
            meta[416 + e] = yoff;
            for (int i = 0; i < padded; i += 256) {
                meta[32 + idx] = e; meta[160 + idx] = i; meta[288 + idx] = yoff + i; idx++;
            }
            yoff += n;
        }
        meta[17] = idx;
    }
    __syncthreads();
    for (int e = 0; e < NET; e++)
        for (int i = sN[e] + tid; i < sPad[e]; i += 256) {
            tok[e * CAP + i] = 0; wgt[e * CAP + i] = 0.f;
        }
}

// ---------------- grouped up-GEMM + SiLU (round-9 structure + counted vmcnt) ----------------
// BM=256, 128 gate + 128 up cols, BK=64, 16 K-tiles, 512 thr (8 waves 4Mx2N),
// 2 dbuf x 64KB. Per tile: sched_barrier pin; STAGE(t+1); vmcnt(8) = wait
// stage(t) only (stage(t+1) stays in flight across the barrier); opening
// s_barrier; ds+MFMA; pin; trailing s_barrier. No vmcnt(0) drain in loop.
__global__ __launch_bounds__(512, 2) void k_up(const ushort* __restrict__ xb,
                                               const ushort* __restrict__ wupT,
                                               ushort* __restrict__ act,
                                               const int* __restrict__ tok,
                                               const int* __restrict__ meta) {
    __shared__ __align__(16) char smem[131072];
    int bid = blockIdx.x;
    int s = (bid & 7) * CPX + (bid >> 3);     // XCD swizzle: 4 cb of one rb per XCD
    int rb = s >> 2, cb = s & 3;
    if (rb >= meta[17]) return;
    int e = meta[32 + rb], rloc = meta[160 + rb], abrow = meta[288 + rb];
    int ne = meta[e];
    int tid = threadIdx.x, lane = tid & 63, wave = tid >> 6;

    int srow = tid >> 3;                       // 0..63 (row within 64-row issue)
    int col16 = (tid & 7) << 4;
    int swz = col16 ^ ((srow & 7) << 4);
    const int listBase = e * CAP + rloc;
    int tokr[4];
#pragma unroll
    for (int i = 0; i < 4; i++) tokr[i] = tok[listBase + i * 64 + srow];
    const char* xbase = (const char*)xb;
    const char* wb = (const char*)wupT + (size_t)e * 2097152;
    int ldsl = wave * 1024;

    int wr = wave >> 1, wc = wave & 1;
    int lr = lane & 15, lk = lane >> 4;
    int aOff = (wr * 64 + lr) * 128;
    int bOff = (wc * 64 + lr) * 128;
    int kp0 = (lk * 16) ^ ((lr & 7) << 4);
    int kp1 = (64 + lk * 16) ^ ((lr & 7) << 4);

    f32x4 accg[4][4], accu[4][4];
#pragma unroll
    for (int m = 0; m < 4; m++)
#pragma unroll
        for (int n = 0; n < 4; n++) {
            accg[m][n] = (f32x4){0.f, 0.f, 0.f, 0.f};
            accu[m][n] = (f32x4){0.f, 0.f, 0.f, 0.f};
        }

#define STAGE_UP(KT)                                                                      \
    {                                                                                     \
        char* base = smem + ((KT) & 1) * 65536;                                           \
        int kB = (KT) * 128;                                                              \
        _Pragma("unroll")                                                                 \
        for (int i = 0; i < 4; i++)                                                       \
            gload16(xbase + (size_t)tokr[i] * 2048 + kB + swz, base + i * 8192 + ldsl);   \
        _Pragma("unroll")                                                                 \
        for (int i = 0; i < 2; i++)                                                       \
            gload16(wb + (size_t)(cb * 128 + i * 64 + srow) * 2048 + kB + swz,            \
                    base + 32768 + i * 8192 + ldsl);                                      \
        _Pragma("unroll")                                                                 \
        for (int i = 0; i < 2; i++)                                                       \
            gload16(wb + (size_t)(512 + cb * 128 + i * 64 + srow) * 2048 + kB + swz,      \
                    base + 49152 + i * 8192 + ldsl);                                      \
    }

    STAGE_UP(0);
#pragma unroll 1
    for (int kt = 0; kt < 16; ++kt) {
        __builtin_amdgcn_sched_barrier(0);     // pin: STAGE may not hoist above trailing barrier
        if (kt < 15) STAGE_UP(kt + 1);
        if (kt < 15) { asm volatile("s_waitcnt vmcnt(8)" ::: "memory"); }
        else         { asm volatile("s_waitcnt vmcnt(0)" ::: "memory"); }
        __builtin_amdgcn_s_barrier();          // all waves: stage(kt) landed
        __builtin_amdgcn_sched_barrier(0);     // pin: reads may not hoist above barrier
        const char* A  = smem + (kt & 1) * 65536;
        const char* Bg = A + 32768;
        const char* Bu = A + 49152;
        __builtin_amdgcn_s_setprio(1);
#pragma unroll
        for (int kk = 0; kk < 2; kk++) {
            int kp = kk ? kp1 : kp0;
            bf16x8 a[4], bg[4], bu[4];
#pragma unroll
            for (int m = 0; m < 4; m++) a[m] = *(const bf16x8*)(A + aOff + m * 2048 + kp);
#pragma unroll
            for (int n = 0; n < 4; n++) bg[n] = *(const bf16x8*)(Bg + bOff + n * 2048 + kp);
#pragma unroll
            for (int n = 0; n < 4; n++) bu[n] = *(const bf16x8*)(Bu + bOff + n * 2048 + kp);
#pragma unroll
            for (int m = 0; m < 4; m++)
#pragma unroll
                for (int n = 0; n < 4; n++) {
                    accg[m][n] = __builtin_amdgcn_mfma_f32_16x16x32_bf16(a[m], bg[n], accg[m][n], 0, 0, 0);
                    accu[m][n] = __builtin_amdgcn_mfma_f32_16x16x32_bf16(a[m], bu[n], accu[m][n], 0, 0, 0);
                }
        }
        __builtin_amdgcn_s_setprio(0);
        __builtin_amdgcn_sched_barrier(0);     // pin: nothing from next iter crosses back
        __builtin_amdgcn_s_barrier();          // reads of buf[kt] done before it is re-staged
    }
    __syncthreads();
    // SiLU(gate)*up -> bf16, stage in LDS [256][128]
    ushort* actl = (ushort*)smem;
#pragma unroll
    for (int m = 0; m < 4; m++)
#pragma unroll
        for (int n = 0; n < 4; n++)
#pragma unroll
            for (int j = 0; j < 4; j++) {
                float gv = accg[m][n][j];
                float uv = accu[m][n][j];
                float av = (gv / (1.f + __expf(-gv))) * uv;
                int row = wr * 64 + m * 16 + lk * 4 + j;
                int col = wc * 64 + n * 16 + lr;
                actl[row * 128 + col] = f2bf(av);
            }
    __syncthreads();
#pragma unroll
    for (int p = 0; p < 8; p++) {
        int c = p * 512 + tid;
        int row = c >> 4, off = (c & 15) << 4;
        if (rloc + row < ne)
            *(uint4*)((char*)act + (size_t)(abrow + row) * 1024 + cb * 256 + off) =
                *(const uint4*)((const char*)actl + row * 256 + off);
    }
#undef STAGE_UP
}

// ---------------- grouped down-GEMM + weighted bf16 store (round-9 + counted vmcnt) ----------------
// BM=256, BN=256, BK=64, 8 K-tiles, 512 thr (8 waves 4Mx2N, 64x128 per wave),
// 2 dbuf x 64KB, vmcnt(8) steady (8 loads/thread per stage).
__global__ __launch_bounds__(512, 2) void k_down(const ushort* __restrict__ act,
                                                 const ushort* __restrict__ wdT,
                                                 ushort* __restrict__ ybuf,
                                                 const float* __restrict__ wgt,
                                                 const int* __restrict__ meta) {
    __shared__ __align__(16) char smem[131072];
    int bid = blockIdx.x;
    int s = (bid & 7) * CPX + (bid >> 3);
    int rb = s >> 2, cb = s & 3;
    if (rb >= meta[17]) return;
    int e = meta[32 + rb], rloc = meta[160 + rb], abrow = meta[288 + rb];
    int ne = meta[e];
    int tid = threadIdx.x, lane = tid & 63, wave = tid >> 6;

    int srow = tid >> 3;
    int col16 = (tid & 7) << 4;
    int swz = col16 ^ ((srow & 7) << 4);
    const char* abase = (const char*)act + (size_t)abrow * 1024;
    const char* bbase = (const char*)wdT + (size_t)e * 1048576 + (size_t)cb * 256 * 1024;
    int ldsl = wave * 1024;

    int wr = wave >> 1, wc = wave & 1;
    int lr = lane & 15, lk = lane >> 4;
    int aOff = (wr * 64 + lr) * 128;
    int bOff = (wc * 128 + lr) * 128;
    int kp0 = (lk * 16) ^ ((lr & 7) << 4);
    int kp1 = (64 + lk * 16) ^ ((lr & 7) << 4);

    f32x4 acc[4][8];
#pragma unroll
    for (int m = 0; m < 4; m++)
#pragma unroll
        for (int n = 0; n < 8; n++) acc[m][n] = (f32x4){0.f, 0.f, 0.f, 0.f};

#define STAGE_DN(KT)                                                                     \
    {                                                                                    \
        char* base = smem + ((KT) & 1) * 65536;                                          \
        int kB = (KT) * 128;                                                             \
        _Pragma("unroll")                                                                \
        for (int i = 0; i < 4; i++)                                                      \
            gload16(abase + (size_t)(i * 64 + srow) * 1024 + kB + swz,                   \
                    base + i * 8192 + ldsl);                                             \
        _Pragma("unroll")                                                                \
        for (int i = 0; i < 4; i++)                                                      \
            gload16(bbase + (size_t)(i * 64 + srow) * 1024 + kB + swz,                   \
                    base + 32768 + i * 8192 + ldsl);                                     \
    }

    STAGE_DN(0);
#pragma unroll 1
    for (int kt = 0; kt < 8; ++kt) {
        __builtin_amdgcn_sched_barrier(0);
        if (kt < 7) STAGE_DN(kt + 1);
        if (kt < 7) { asm volatile("s_waitcnt vmcnt(8)" ::: "memory"); }
        else        { asm volatile("s_waitcnt vmcnt(0)" ::: "memory"); }
        __builtin_amdgcn_s_barrier();
        __builtin_amdgcn_sched_barrier(0);
        const char* A = smem + (kt & 1) * 65536;
        const char* B = A + 32768;
        __builtin_amdgcn_s_setprio(1);
#pragma unroll
        for (int kk = 0; kk < 2; kk++) {
            int kp = kk ? kp1 : kp0;
            bf16x8 a[4], b[8];
#pragma unroll
            for (int m = 0; m < 4; m++) a[m] = *(const bf16x8*)(A + aOff + m * 2048 + kp);
#pragma unroll
            for (int n = 0; n < 8; n++) b[n] = *(const bf16x8*)(B + bOff + n * 2048 + kp);
#pragma unroll
            for (int m = 0; m < 4; m++)
#pragma unroll
                for (int n = 0; n < 8; n++)
                    acc[m][n] = __builtin_amdgcn_mfma_f32_16x16x32_bf16(a[m], b[n], acc[m][n], 0, 0, 0);
        }
        __builtin_amdgcn_s_setprio(0);
        __builtin_amdgcn_sched_barrier(0);
        __builtin_amdgcn_s_barrier();
    }
    __syncthreads();
    // scale by router weight, stage bf16 tile [256][256] in LDS (128KB)
    const int lb = e * CAP + rloc;
    ushort* yl = (ushort*)smem;
#pragma unroll
    for (int m = 0; m < 4; m++)
#pragma unroll
        for (int j = 0; j < 4; j++) {
            int row = wr * 64 + m * 16 + lk * 4 + j;
            float w = wgt[lb + row];
#pragma unroll
            for (int n = 0; n < 8; n++) {
                int col = wc * 128 + n * 16 + lr;
                yl[row * 256 + col] = f2bf(acc[m][n][j] * w);
            }
        }
    __syncthreads();
#pragma unroll
    for (int p = 0; p < 16; p++) {
        int c = p * 512 + tid;
        int row = c >> 5, off = (c & 31) << 4;
        if (rloc + row < ne)
            *(uint4*)((char*)ybuf + (size_t)(abrow + row) * 2048 + cb * 512 + off) =
                *(const uint4*)((const char*)yl + row * 512 + off);
    }
#undef STAGE_DN
}

// ---------------- per-token combine ----------------
__global__ __launch_bounds__(256) void k_combine(const ushort* __restrict__ y,
                                                 const int2* __restrict__ ia,
                                                 const int2* __restrict__ ib,
                                                 const int* __restrict__ meta,
                                                 float* __restrict__ out) {
    int t = blockIdx.x;
    int2 a = ia[t], b = ib[t];
    int r0 = (meta[416 + a.x] + a.y) << 10;
    int r1 = (meta[416 + b.x] + b.y) << 10;
    int rs = (meta[432] + t) << 10;
    int c = threadIdx.x << 2;
    ushort4 va = *(const ushort4*)(y + r0 + c);
    ushort4 vb = *(const ushort4*)(y + r1 + c);
    ushort4 vs = *(const ushort4*)(y + rs + c);
    float4 o;
    o.x = bf2f(va.x) + bf2f(vb.x) + bf2f(vs.x);
    o.y = bf2f(va.y) + bf2f(vb.y) + bf2f(vs.y);
    o.z = bf2f(va.z) + bf2f(vb.z) + bf2f(vs.z);
    o.w = bf2f(va.w) + bf2f(vb.w) + bf2f(vs.w);
    *(float4*)(out + ((size_t)t << 10) + c) = o;
}

extern "C" void kernel_launch(void* const* d_in, const int* in_sizes, int n_in,
                              void* d_out, int out_size, void* d_ws, size_t ws_size,
                              hipStream_t stream) {
    const float* x    = (const float*)d_in[0];
    const float* Wr   = (const float*)d_in[1];
    const float* Wup  = (const float*)d_in[2];
    const float* Wdn  = (const float*)d_in[3];
    const float* Wsup = (const float*)d_in[4];
    const float* Wsdn = (const float*)d_in[5];
    float* out = (float*)d_out;
    float* probs = out + (size_t)T_TOK * HD;

    if (ws_size < WS_NEEDED) return;

    char* ws = (char*)d_ws;
    ushort* xb    = (ushort*)(ws + OFF_XBF);
    ushort* wupT  = (ushort*)(ws + OFF_WUPT);
    ushort* wdT   = (ushort*)(ws + OFF_WDT);
    ushort* act   = (ushort*)(ws + OFF_ACT);
    int2*   inva  = (int2*)(ws + OFF_EIDX);
    int2*   invb  = (int2*)(ws + OFF_EW);
    int*    tok   = (int*)(ws + OFF_TOK);
    float*  wgt   = (float*)(ws + OFF_WGT);
    int*    meta  = (int*)(ws + OFF_META);
    int4*   sel   = (int4*)(ws + OFF_SEL);
    ushort* ybuf  = (ushort*)(ws + OFF_XBF);   // aliases xb+wupT (dead after k_up)

    k_tup<<<NET * 256, 256, 0, stream>>>(Wup, Wsup, wupT);
    k_tdn<<<NET * 128, 256, 0, stream>>>(Wdn, Wsdn, wdT);
    k_router<<<T_TOK / 16, 1024, 0, stream>>>(x, Wr, probs, xb, tok, wgt, sel);
    k_bucket<<<NE, 1024, 0, stream>>>(sel, tok, wgt, inva, invb, meta);
    k_finalize<<<1, 256, 0, stream>>>(meta, tok, wgt);
    k_up<<<MAXWG, 512, 0, stream>>>(xb, wupT, act, tok, meta);
    k_down<<<MAXWG, 512, 0, stream>>>(act, wdT, ybuf, wgt, meta);
    k_combine<<<T_TOK, 256, 0, stream>>>(ybuf, inva, invb, meta, out);
}

// Round 14
// 182.531 us; speedup vs baseline: 1.0925x; 1.0925x over previous
//
#include <hip/hip_runtime.h>
#include <stdint.h>

#define T_TOK 8192
#define HD 1024
#define NE 16
#define NET 17
#define FD 512
#define CAP 8448            // max tokens/expert 8192 + 255 pad (256-row blocks)
#define MAXWG 448           // 112 row-blocks x 4 col-blocks
#define CPX 56              // MAXWG / 8 XCDs

typedef unsigned int uint;
typedef unsigned short ushort;
typedef __attribute__((ext_vector_type(8))) __bf16 bf16x8;
typedef __attribute__((ext_vector_type(4))) float f32x4;

// ws layout (bytes)
#define OFF_XBF   0ull            // 16 MB   (dead after k_up -> ybuf)
#define OFF_WUPT  16777216ull     // 35.65MB (dead after k_up -> ybuf)
#define OFF_WDT   52428800ull     // 17.83MB
#define OFF_ACT   70254592ull     // 24576 x 1024 B = 25.17MB (compact rows)
#define OFF_EIDX  95420416ull     // inv_a (e0,p0) per token
#define OFF_EW    95485952ull     // inv_b (e1,p1) per token
#define OFF_TOK   95551488ull     // 17*CAP ints
#define OFF_WGT   96125952ull
#define OFF_META  96700416ull
#define OFF_SEL   96704512ull     // int4 per token: (i1, i2, w1 bits, w2 bits)
#define WS_NEEDED (OFF_SEL + 131072ull)
// ybuf: compact 24576 rows x 2048 B = 50,331,648 < OFF_WDT.

// meta: [0..16]=cnt (16=shared=8192), [17]=nRB, [32..144)=rbE, [160..272)=rbLoc,
//       [288..400)=rbRow (compact base), [416..433)=ybase per expert

__device__ __forceinline__ ushort f2bf(float f) {
    uint u = __float_as_uint(f);
    u += 0x7FFFu + ((u >> 16) & 1u);
    return (ushort)(u >> 16);
}
__device__ __forceinline__ float bf2f(ushort u) {
    return __uint_as_float(((uint)u) << 16);
}
__device__ __forceinline__ void gload16(const void* g, void* l) {
    __builtin_amdgcn_global_load_lds(
        (const __attribute__((address_space(1))) void*)g,
        (__attribute__((address_space(3))) void*)l, 16, 0, 0);
}

// ---------------- router: NO global atomics, 4-way K-split, 100% occupancy ----------------
__global__ __launch_bounds__(1024) void k_router(const float* __restrict__ x,
                                                 const float* __restrict__ Wr,
                                                 float* __restrict__ probs,
                                                 ushort* __restrict__ xb,
                                                 int* __restrict__ tok,
                                                 float* __restrict__ wgt,
                                                 int4* __restrict__ sel) {
    __shared__ __align__(16) float wr_s[HD * NE];   // 64 KB fp32
    int tid = threadIdx.x;
    int t0 = blockIdx.x * 16;
#pragma unroll
    for (int i = 0; i < 4; ++i) {
        int idx = (i * 1024 + tid) * 4;
        *(float4*)(&wr_s[idx]) = *(const float4*)(Wr + idx);
    }
#pragma unroll
    for (int p = 0; p < 4; ++p) {
        int r = p * 4 + (tid >> 8);
        int c = (tid & 255) * 4;
        float4 v = *(const float4*)(x + (size_t)(t0 + r) * HD + c);
        ushort4 cc;
        cc.x = f2bf(v.x); cc.y = f2bf(v.y); cc.z = f2bf(v.z); cc.w = f2bf(v.w);
        *(ushort4*)(xb + (size_t)(t0 + r) * HD + c) = cc;
    }
    __syncthreads();
    int t = t0 + (tid >> 6);
    int sub = tid & 63;
    int e = sub & 15, kp = sub >> 4;
    const float* xg = x + (size_t)t * HD + kp * 256;
    const int wb = kp * 256 * NE + e;
    float s0 = 0.f, s1 = 0.f;
#pragma unroll 8
    for (int j = 0; j < 256; j += 4) {
        float4 v = *(const float4*)(xg + j);
        s0 = fmaf(v.x, wr_s[wb + (j + 0) * NE], s0);
        s1 = fmaf(v.y, wr_s[wb + (j + 1) * NE], s1);
        s0 = fmaf(v.z, wr_s[wb + (j + 2) * NE], s0);
        s1 = fmaf(v.w, wr_s[wb + (j + 3) * NE], s1);
    }
    float s = s0 + s1;
    s += __shfl_xor(s, 16);
    s += __shfl_xor(s, 32);
    float m = s;
#pragma unroll
    for (int w = 1; w < 16; w <<= 1) m = fmaxf(m, __shfl_xor(m, w));
    float p = __expf(s - m);
    float sum = p;
#pragma unroll
    for (int w = 1; w < 16; w <<= 1) sum += __shfl_xor(sum, w);
    p /= sum;
    if (kp == 0) probs[(size_t)t * NE + e] = p;
    float m1 = p;
#pragma unroll
    for (int w = 1; w < 16; w <<= 1) m1 = fmaxf(m1, __shfl_xor(m1, w));
    unsigned long long bal = __ballot(p == m1);
    int i1 = __ffs((int)((bal >> (kp * 16)) & 0xFFFFu)) - 1;
    float p2v = (e == i1) ? -1.f : p;
    float m2 = p2v;
#pragma unroll
    for (int w = 1; w < 16; w <<= 1) m2 = fmaxf(m2, __shfl_xor(m2, w));
    bal = __ballot(p2v == m2);
    int i2 = __ffs((int)((bal >> (kp * 16)) & 0xFFFFu)) - 1;
    if (sub == 0) {
        float inv2 = 1.f / (m1 + m2 + 1e-9f);
        sel[t] = make_int4(i1, i2, __float_as_int(m1 * inv2), __float_as_int(m2 * inv2));
        tok[16 * CAP + t] = t;
        wgt[16 * CAP + t] = 1.f;
    }
}

// ---------------- bucket: 16 blocks (one per expert), 16 waves scan 512-token chunks ----------------
__global__ __launch_bounds__(1024) void k_bucket(const int4* __restrict__ sel,
                                                 int* __restrict__ tok,
                                                 float* __restrict__ wgt,
                                                 int2* __restrict__ inva,
                                                 int2* __restrict__ invb,
                                                 int* __restrict__ meta) {
    __shared__ int wcnt[16], wbase[16];
    int e = blockIdx.x;
    int wave = threadIdx.x >> 6;
    int lane = threadIdx.x & 63;
    unsigned long long ltmask = (1ull << lane) - 1ull;
    int tstart = wave * 512;
    int cnt = 0;
#pragma unroll
    for (int it = 0; it < 8; ++it) {
        int4 s = sel[tstart + it * 64 + lane];
        cnt += (int)__popcll(__ballot(s.x == e)) + (int)__popcll(__ballot(s.y == e));
    }
    if (lane == 0) wcnt[wave] = cnt;
    __syncthreads();
    if (threadIdx.x == 0) {
        int acc = 0;
#pragma unroll
        for (int w = 0; w < 16; ++w) { wbase[w] = acc; acc += wcnt[w]; }
        meta[e] = acc;
    }
    __syncthreads();
    int pos = wbase[wave];
#pragma unroll
    for (int it = 0; it < 8; ++it) {
        int t = tstart + it * 64 + lane;
        int4 s = sel[t];
        bool m1 = (s.x == e), m2 = (s.y == e);
        unsigned long long b1 = __ballot(m1), b2 = __ballot(m2);
        int c1 = (int)__popcll(b1);
        if (m1) {
            int q = pos + (int)__popcll(b1 & ltmask);
            tok[e * CAP + q] = t; wgt[e * CAP + q] = __int_as_float(s.z);
            inva[t] = make_int2(e, q);
        }
        if (m2) {
            int q = pos + c1 + (int)__popcll(b2 & ltmask);
            tok[e * CAP + q] = t; wgt[e * CAP + q] = __int_as_float(s.w);
            invb[t] = make_int2(e, q);
        }
        pos += c1 + (int)__popcll(b2);
    }
}

// ---------------- fused weight transposes: W_up and W_dn -> bf16 [n][k], 64x64 tiles ----------------
// blocks [0, 4352): W_up [E][H][2F] -> wupT [17][2F][H]
// blocks [4352, 6528): W_dn [E][F][H] -> wdT [17][H][F]
__global__ __launch_bounds__(256) void k_tw(const float* __restrict__ Wup,
                                            const float* __restrict__ Wsup,
                                            const float* __restrict__ Wdn,
                                            const float* __restrict__ Wsdn,
                                            ushort* __restrict__ dstUp,
                                            ushort* __restrict__ dstDn) {
    __shared__ __align__(16) float tile[64][68];
    int bid = blockIdx.x;
    int tid = threadIdx.x;
    int rr = tid >> 4, cc = (tid & 15) * 4;
    const float* src;
    ushort* dst;
    size_t srcRowStride, dstRowStride;
    int r0, c0;   // src tile origin (rows x 1024 cols layout in both cases)
    if (bid < NET * 256) {
        int e = bid >> 8, rem = bid & 255;
        int h0 = (rem >> 4) * 64, n0 = (rem & 15) * 64;
        src = ((e < 16) ? (Wup + (size_t)e * HD * 1024) : Wsup);
        dst = dstUp + (size_t)e * 1048576;
        r0 = h0; c0 = n0; srcRowStride = 1024; dstRowStride = 1024;
    } else {
        int b2 = bid - NET * 256;
        int e = b2 >> 7, rem = b2 & 127;
        int f0 = (rem >> 4) * 64, h0 = (rem & 15) * 64;
        src = ((e < 16) ? (Wdn + (size_t)e * FD * HD) : Wsdn);
        dst = dstDn + (size_t)e * 524288;
        r0 = f0; c0 = h0; srcRowStride = 1024; dstRowStride = 512;
    }
#pragma unroll
    for (int q = 0; q < 4; ++q) {
        float4 v = *(const float4*)(src + (size_t)(r0 + q * 16 + rr) * srcRowStride + c0 + cc);
        *(float4*)(&tile[q * 16 + rr][cc]) = v;
    }
    __syncthreads();
#pragma unroll
    for (int q = 0; q < 4; ++q) {
        int nl = q * 16 + rr;
        ushort4 o;
        o.x = f2bf(tile[cc + 0][nl]);
        o.y = f2bf(tile[cc + 1][nl]);
        o.z = f2bf(tile[cc + 2][nl]);
        o.w = f2bf(tile[cc + 3][nl]);
        *(ushort4*)(dst + (size_t)(c0 + nl) * dstRowStride + r0 + cc) = o;
    }
}

// ---------------- finalize: build 256-row blocks, zero pad slots ----------------
__global__ void k_finalize(int* __restrict__ meta, int* __restrict__ tok,
                           float* __restrict__ wgt) {
    __shared__ int sN[NET], sPad[NET];
    int tid = threadIdx.x;
    if (tid == 0) {
        meta[16] = T_TOK;
        int idx = 0, yoff = 0;
        for (int e = 0; e < NET; e++) {
            int n = meta[e];
            int padded = (n + 255) & ~255;
            sN[e] = n; sPad[e] = padded;
            meta[416 + e] = yoff;
            for (int i = 0; i < padded; i += 256) {
                meta[32 + idx] = e; meta[160 + idx] = i; meta[288 + idx] = yoff + i; idx++;
            }
            yoff += n;
        }
        meta[17] = idx;
    }
    __syncthreads();
    for (int e = 0; e < NET; e++)
        for (int i = sN[e] + tid; i < sPad[e]; i += 256) {
            tok[e * CAP + i] = 0; wgt[e * CAP + i] = 0.f;
        }
}

// ---------------- grouped up-GEMM + SiLU (round-9 champion structure) ----------------
// BM=256, cols 128 gate + 128 up per block, BK=64, 512 thr (8 waves 4Mx2N),
// double-buffered LDS (2 x {A 32K | Bg 16K | Bu 16K}), depth-1 prefetch.
__global__ __launch_bounds__(512, 2) void k_up(const ushort* __restrict__ xb,
                                               const ushort* __restrict__ wupT,
                                               ushort* __restrict__ act,
                                               const int* __restrict__ tok,
                                               const int* __restrict__ meta) {
    __shared__ __align__(16) char smem[131072];
    int bid = blockIdx.x;
    int s = (bid & 7) * CPX + (bid >> 3);     // XCD swizzle: 4 cb of one rb per XCD
    int rb = s >> 2, cb = s & 3;
    if (rb >= meta[17]) return;
    int e = meta[32 + rb], rloc = meta[160 + rb], abrow = meta[288 + rb];
    int ne = meta[e];
    int tid = threadIdx.x, lane = tid & 63, wave = tid >> 6;

    int srow = tid >> 3;                       // 0..63 (row within 64-row issue)
    int col16 = (tid & 7) << 4;
    int swz = col16 ^ ((srow & 7) << 4);
    const int listBase = e * CAP + rloc;
    int tokr[4];
#pragma unroll
    for (int i = 0; i < 4; i++) tokr[i] = tok[listBase + i * 64 + srow];
    const char* xbase = (const char*)xb;
    const char* wb = (const char*)wupT + (size_t)e * 2097152;
    int ldsl = wave * 1024;                    // wave-uniform LDS slot within each 8KB issue

    int wr = wave >> 1, wc = wave & 1;
    int lr = lane & 15, lk = lane >> 4;
    int aOff = (wr * 64 + lr) * 128;
    int bOff = (wc * 64 + lr) * 128;
    int kp0 = (lk * 16) ^ ((lr & 7) << 4);
    int kp1 = (64 + lk * 16) ^ ((lr & 7) << 4);

    f32x4 accg[4][4], accu[4][4];
#pragma unroll
    for (int m = 0; m < 4; m++)
#pragma unroll
        for (int n = 0; n < 4; n++) {
            accg[m][n] = (f32x4){0.f, 0.f, 0.f, 0.f};
            accu[m][n] = (f32x4){0.f, 0.f, 0.f, 0.f};
        }

#define STAGE_UP(KT, D)                                                                   \
    {                                                                                     \
        char* base = smem + (D) * 65536;                                                  \
        int kB = (KT) * 128;                                                              \
        _Pragma("unroll")                                                                 \
        for (int i = 0; i < 4; i++)                                                       \
            gload16(xbase + (size_t)tokr[i] * 2048 + kB + swz, base + i * 8192 + ldsl);   \
        _Pragma("unroll")                                                                 \
        for (int i = 0; i < 2; i++)                                                       \
            gload16(wb + (size_t)(cb * 128 + i * 64 + srow) * 2048 + kB + swz,            \
                    base + 32768 + i * 8192 + ldsl);                                      \
        _Pragma("unroll")                                                                 \
        for (int i = 0; i < 2; i++)                                                       \
            gload16(wb + (size_t)(512 + cb * 128 + i * 64 + srow) * 2048 + kB + swz,      \
                    base + 49152 + i * 8192 + ldsl);                                      \
    }

    STAGE_UP(0, 0);
    asm volatile("s_waitcnt vmcnt(0)" ::: "memory");
    __syncthreads();
    int cur = 0;
#pragma unroll 1
    for (int kt = 0; kt < 16; ++kt) {
        if (kt < 15) STAGE_UP(kt + 1, cur ^ 1);
        const char* A  = smem + cur * 65536;
        const char* Bg = A + 32768;
        const char* Bu = A + 49152;
#pragma unroll
        for (int kk = 0; kk < 2; kk++) {
            int kp = kk ? kp1 : kp0;
            bf16x8 a[4], bg[4], bu[4];
#pragma unroll
            for (int m = 0; m < 4; m++) a[m] = *(const bf16x8*)(A + aOff + m * 2048 + kp);
#pragma unroll
            for (int n = 0; n < 4; n++) bg[n] = *(const bf16x8*)(Bg + bOff + n * 2048 + kp);
#pragma unroll
            for (int n = 0; n < 4; n++) bu[n] = *(const bf16x8*)(Bu + bOff + n * 2048 + kp);
#pragma unroll
            for (int m = 0; m < 4; m++)
#pragma unroll
                for (int n = 0; n < 4; n++) {
                    accg[m][n] = __builtin_amdgcn_mfma_f32_16x16x32_bf16(a[m], bg[n], accg[m][n], 0, 0, 0);
                    accu[m][n] = __builtin_amdgcn_mfma_f32_16x16x32_bf16(a[m], bu[n], accu[m][n], 0, 0, 0);
                }
        }
        asm volatile("s_waitcnt vmcnt(0)" ::: "memory");
        __syncthreads();
        cur ^= 1;
    }
    // SiLU(gate)*up -> bf16, stage in LDS [256][128]
    ushort* actl = (ushort*)smem;
#pragma unroll
    for (int m = 0; m < 4; m++)
#pragma unroll
        for (int n = 0; n < 4; n++)
#pragma unroll
            for (int j = 0; j < 4; j++) {
                float gv = accg[m][n][j];
                float uv = accu[m][n][j];
                float av = (gv / (1.f + __expf(-gv))) * uv;
                int row = wr * 64 + m * 16 + lk * 4 + j;
                int col = wc * 64 + n * 16 + lr;
                actl[row * 128 + col] = f2bf(av);
            }
    __syncthreads();
#pragma unroll
    for (int p = 0; p < 8; p++) {
        int c = p * 512 + tid;
        int row = c >> 4, off = (c & 15) << 4;
        if (rloc + row < ne)
            *(uint4*)((char*)act + (size_t)(abrow + row) * 1024 + cb * 256 + off) =
                *(const uint4*)((const char*)actl + row * 256 + off);
    }
#undef STAGE_UP
}

// ---------------- grouped down-GEMM + weighted bf16 store (round-9 champion) ----------------
// BM=256, BN=256, BK=64, K=512, 512 thr (8 waves 4Mx2N, 64x128 per wave),
// double-buffered LDS (2 x {A 32K | B 32K}), depth-1 prefetch.
__global__ __launch_bounds__(512, 2) void k_down(const ushort* __restrict__ act,
                                                 const ushort* __restrict__ wdT,
                                                 ushort* __restrict__ ybuf,
                                                 const float* __restrict__ wgt,
                                                 const int* __restrict__ meta) {
    __shared__ __align__(16) char smem[131072];
    int bid = blockIdx.x;
    int s = (bid & 7) * CPX + (bid >> 3);
    int rb = s >> 2, cb = s & 3;
    if (rb >= meta[17]) return;
    int e = meta[32 + rb], rloc = meta[160 + rb], abrow = meta[288 + rb];
    int ne = meta[e];
    int tid = threadIdx.x, lane = tid & 63, wave = tid >> 6;

    int srow = tid >> 3;
    int col16 = (tid & 7) << 4;
    int swz = col16 ^ ((srow & 7) << 4);
    const char* abase = (const char*)act + (size_t)abrow * 1024;
    const char* bbase = (const char*)wdT + (size_t)e * 1048576 + (size_t)cb * 256 * 1024;
    int ldsl = wave * 1024;

    int wr = wave >> 1, wc = wave & 1;
    int lr = lane & 15, lk = lane >> 4;
    int aOff = (wr * 64 + lr) * 128;
    int bOff = (wc * 128 + lr) * 128;
    int kp0 = (lk * 16) ^ ((lr & 7) << 4);
    int kp1 = (64 + lk * 16) ^ ((lr & 7) << 4);

    f32x4 acc[4][8];
#pragma unroll
    for (int m = 0; m < 4; m++)
#pragma unroll
        for (int n = 0; n < 8; n++) acc[m][n] = (f32x4){0.f, 0.f, 0.f, 0.f};

#define STAGE_DN(KT, D)                                                                  \
    {                                                                                    \
        char* base = smem + (D) * 65536;                                                 \
        int kB = (KT) * 128;                                                             \
        _Pragma("unroll")                                                                \
        for (int i = 0; i < 4; i++)                                                      \
            gload16(abase + (size_t)(i * 64 + srow) * 1024 + kB + swz,                   \
                    base + i * 8192 + ldsl);                                             \
        _Pragma("unroll")                                                                \
        for (int i = 0; i < 4; i++)                                                      \
            gload16(bbase + (size_t)(i * 64 + srow) * 1024 + kB + swz,                   \
                    base + 32768 + i * 8192 + ldsl);                                     \
    }

    STAGE_DN(0, 0);
    asm volatile("s_waitcnt vmcnt(0)" ::: "memory");
    __syncthreads();
    int cur = 0;
#pragma unroll 1
    for (int kt = 0; kt < 8; ++kt) {
        if (kt < 7) STAGE_DN(kt + 1, cur ^ 1);
        const char* A = smem + cur * 65536;
        const char* B = A + 32768;
#pragma unroll
        for (int kk = 0; kk < 2; kk++) {
            int kp = kk ? kp1 : kp0;
            bf16x8 a[4], b[8];
#pragma unroll
            for (int m = 0; m < 4; m++) a[m] = *(const bf16x8*)(A + aOff + m * 2048 + kp);
#pragma unroll
            for (int n = 0; n < 8; n++) b[n] = *(const bf16x8*)(B + bOff + n * 2048 + kp);
#pragma unroll
            for (int m = 0; m < 4; m++)
#pragma unroll
                for (int n = 0; n < 8; n++)
                    acc[m][n] = __builtin_amdgcn_mfma_f32_16x16x32_bf16(a[m], b[n], acc[m][n], 0, 0, 0);
        }
        asm volatile("s_waitcnt vmcnt(0)" ::: "memory");
        __syncthreads();
        cur ^= 1;
    }
    __syncthreads();
    // scale by router weight, stage bf16 tile [256][256] in LDS (128KB)
    const int lb = e * CAP + rloc;
    ushort* yl = (ushort*)smem;
#pragma unroll
    for (int m = 0; m < 4; m++)
#pragma unroll
        for (int j = 0; j < 4; j++) {
            int row = wr * 64 + m * 16 + lk * 4 + j;
            float w = wgt[lb + row];
#pragma unroll
            for (int n = 0; n < 8; n++) {
                int col = wc * 128 + n * 16 + lr;
                yl[row * 256 + col] = f2bf(acc[m][n][j] * w);
            }
        }
    __syncthreads();
#pragma unroll
    for (int p = 0; p < 16; p++) {
        int c = p * 512 + tid;
        int row = c >> 5, off = (c & 31) << 4;
        if (rloc + row < ne)
            *(uint4*)((char*)ybuf + (size_t)(abrow + row) * 2048 + cb * 512 + off) =
                *(const uint4*)((const char*)yl + row * 512 + off);
    }
#undef STAGE_DN
}

// ---------------- per-token combine ----------------
__global__ __launch_bounds__(256) void k_combine(const ushort* __restrict__ y,
                                                 const int2* __restrict__ ia,
                                                 const int2* __restrict__ ib,
                                                 const int* __restrict__ meta,
                                                 float* __restrict__ out) {
    int t = blockIdx.x;
    int2 a = ia[t], b = ib[t];
    int r0 = (meta[416 + a.x] + a.y) << 10;
    int r1 = (meta[416 + b.x] + b.y) << 10;
    int rs = (meta[432] + t) << 10;
    int c = threadIdx.x << 2;
    ushort4 va = *(const ushort4*)(y + r0 + c);
    ushort4 vb = *(const ushort4*)(y + r1 + c);
    ushort4 vs = *(const ushort4*)(y + rs + c);
    float4 o;
    o.x = bf2f(va.x) + bf2f(vb.x) + bf2f(vs.x);
    o.y = bf2f(va.y) + bf2f(vb.y) + bf2f(vs.y);
    o.z = bf2f(va.z) + bf2f(vb.z) + bf2f(vs.z);
    o.w = bf2f(va.w) + bf2f(vb.w) + bf2f(vs.w);
    *(float4*)(out + ((size_t)t << 10) + c) = o;
}

extern "C" void kernel_launch(void* const* d_in, const int* in_sizes, int n_in,
                              void* d_out, int out_size, void* d_ws, size_t ws_size,
                              hipStream_t stream) {
    const float* x    = (const float*)d_in[0];
    const float* Wr   = (const float*)d_in[1];
    const float* Wup  = (const float*)d_in[2];
    const float* Wdn  = (const float*)d_in[3];
    const float* Wsup = (const float*)d_in[4];
    const float* Wsdn = (const float*)d_in[5];
    float* out = (float*)d_out;
    float* probs = out + (size_t)T_TOK * HD;

    if (ws_size < WS_NEEDED) return;

    char* ws = (char*)d_ws;
    ushort* xb    = (ushort*)(ws + OFF_XBF);
    ushort* wupT  = (ushort*)(ws + OFF_WUPT);
    ushort* wdT   = (ushort*)(ws + OFF_WDT);
    ushort* act   = (ushort*)(ws + OFF_ACT);
    int2*   inva  = (int2*)(ws + OFF_EIDX);
    int2*   invb  = (int2*)(ws + OFF_EW);
    int*    tok   = (int*)(ws + OFF_TOK);
    float*  wgt   = (float*)(ws + OFF_WGT);
    int*    meta  = (int*)(ws + OFF_META);
    int4*   sel   = (int4*)(ws + OFF_SEL);
    ushort* ybuf  = (ushort*)(ws + OFF_XBF);   // aliases xb+wupT (dead after k_up)

    k_tw<<<NET * 256 + NET * 128, 256, 0, stream>>>(Wup, Wsup, Wdn, Wsdn, wupT, wdT);
    k_router<<<T_TOK / 16, 1024, 0, stream>>>(x, Wr, probs, xb, tok, wgt, sel);
    k_bucket<<<NE, 1024, 0, stream>>>(sel, tok, wgt, inva, invb, meta);
    k_finalize<<<1, 256, 0, stream>>>(meta, tok, wgt);
    k_up<<<MAXWG, 512, 0, stream>>>(xb, wupT, act, tok, meta);
    k_down<<<MAXWG, 512, 0, stream>>>(act, wdT, ybuf, wgt, meta);
    k_combine<<<T_TOK, 256, 0, stream>>>(ybuf, inva, invb, meta, out);
}